// Round 5
// baseline (417.308 us; speedup 1.0000x reference)
//
#include <hip/hip_runtime.h>
#include <math.h>

// ---------------- shared wave reductions ----------------
__device__ __forceinline__ float waveReduceMax(float v) {
#pragma unroll
    for (int off = 32; off > 0; off >>= 1)
        v = fmaxf(v, __shfl_down(v, off, 64));
    return v;
}
__device__ __forceinline__ float waveReduceSum(float v) {
#pragma unroll
    for (int off = 32; off > 0; off >>= 1)
        v += __shfl_down(v, off, 64);
    return v;
}

// ---------------- wave0 solve (proven exact in R0-R4, absmax=0) ----------------
// s_cand holds u = (x - rowmax)/2 values (k entries; extras with u far below
// tau are harmless: they contribute 0 to f(tau) on [-1,0] and self-exclude
// from the support filter). Called by wave 0 only.
#define NREG 12
__device__ __forceinline__ void solve_wave0(const float* s_cand, int k,
                                            float rowmax, float xt,
                                            float inv_n, float* out, int lane)
{
    float ur[NREG];
#pragma unroll
    for (int j = 0; j < NREG; ++j) {
        int idx = lane + 64 * j;
        ur[j] = (idx < k) ? s_cand[idx] : -1e30f;   // sentinel: never in support
    }

    // bisection: f(tau)=sum max(u-tau,0)^2 monotone decreasing;
    // u=0 (rowmax) is always present => f(-1)>=1>=f(0), tau* in [-1,0]
    float lo = -1.0f, hi = 0.0f;
    for (int it = 0; it < 18; ++it) {
        float tau = 0.5f * (lo + hi);
        float acc = 0.0f;
#pragma unroll
        for (int j = 0; j < NREG; ++j) {
            float u = ur[j] - tau;
            acc += (u > 0.0f) ? u * u : 0.0f;
        }
        for (int j = 64 * NREG + lane; j < k; j += 64) {   // LDS tail
            float u = s_cand[j] - tau;
            if (u > 0.0f) acc += u * u;
        }
        float tot = waveReduceSum(acc);
        tot = __shfl(tot, 0, 64);
        if (tot >= 1.0f) lo = tau; else hi = tau;
    }
    const float tau_b = 0.5f * (lo + hi);

    // exact closed form on identified support: tau* = mean - sqrt((1-ss)/k)
    float s1 = 0.0f, s2 = 0.0f, sc = 0.0f;
#pragma unroll
    for (int j = 0; j < NREG; ++j) {
        float u = ur[j];
        if (u > tau_b) { s1 += u; s2 += u * u; sc += 1.0f; }
    }
    for (int j = 64 * NREG + lane; j < k; j += 64) {
        float u = s_cand[j];
        if (u > tau_b) { s1 += u; s2 += u * u; sc += 1.0f; }
    }
    s1 = waveReduceSum(s1); s1 = __shfl(s1, 0, 64);
    s2 = waveReduceSum(s2); s2 = __shfl(s2, 0, 64);
    sc = waveReduceSum(sc); sc = __shfl(sc, 0, 64);
    float mean  = s1 / sc;
    float ss    = s2 - s1 * mean;
    float delta = (1.0f - ss) / sc;
    if (delta < 0.0f) delta = 0.0f;
    const float tau_star = mean - sqrtf(delta);

    // loss: sum p^{3/2} = sum u^3;  dot(p,x) with x = 2u + rowmax
    float p32 = 0.0f, dot = 0.0f;
#pragma unroll
    for (int j = 0; j < NREG; ++j) {
        float u = ur[j] - tau_star;
        if (u > 0.0f) {
            float p = u * u;
            p32 += p * u;
            dot += p * (2.0f * ur[j] + rowmax);
        }
    }
    for (int j = 64 * NREG + lane; j < k; j += 64) {
        float uc = s_cand[j];
        float u  = uc - tau_star;
        if (u > 0.0f) {
            float p = u * u;
            p32 += p * u;
            dot += p * (2.0f * uc + rowmax);
        }
    }
    p32 = waveReduceSum(p32);
    dot = waveReduceSum(dot);
    if (lane == 0) {
        float loss = (1.0f - p32) * (4.0f / 3.0f) + dot - xt;
        atomicAdd(out, loss * inv_n);
    }
}

// ================= two-kernel split (R5) =================
// Pass 1: pure streaming candidate collector. One 256-thr block per 8192-elem
// chunk (no row-wide barrier, no serial solve on the BW-critical path). Chunk
// candidates use threshold chunkmax-2: since rowmax >= chunkmax, this is a
// SUPERSET of the true candidate set {x >= rowmax-2}; extras are inert in the
// solve. Every chunk's max is stored, so rowmax = max over the row's stored
// values. Small blocks + ~52 VGPR => deep occupancy; other blocks' loads
// cover each block's ~1us compact phase (the fill kernels prove this shape
// sustains ~6.7 TB/s).
#define P1_BLOCK 256
#define P1_NV 8
#define CHUNK4 (P1_BLOCK * P1_NV)     // 2048 float4 = 8192 floats per chunk
#define P1_LDSCAP 2048                // per-chunk candidate cap (8 KB LDS)
#define CAP_WS 4096                   // per-row workspace candidate cap

__global__ __launch_bounds__(P1_BLOCK, 8) void tsallis15_pass1(
    const float* __restrict__ x, float* __restrict__ cand,
    int* __restrict__ cnt, int* __restrict__ ovf, int n, int d, int cpr)
{
    __shared__ float s_c[P1_LDSCAP];
    __shared__ float s_red[4];
    __shared__ float s_bcast;
    __shared__ int   s_k, s_base;

    const int bid  = blockIdx.x;
    const int row  = bid / cpr;            // once per block
    const int chk  = bid - row * cpr;
    const int t    = threadIdx.x;
    const int lane = t & 63;
    const int wave = t >> 6;
    const int d4   = d >> 2;
    const float* __restrict__ xr = x + (size_t)row * (size_t)d;
    const float4* __restrict__ xr4 = reinterpret_cast<const float4*>(xr);
    const int c0 = chk * CHUNK4;
    const bool last = (chk == cpr - 1);

    if (t == 0) s_k = 0;

    // ---- chunk -> registers (the only HBM-heavy phase in the kernel) ----
    float4 r[P1_NV];
#pragma unroll
    for (int j = 0; j < P1_NV; ++j) {
        int idx = c0 + t + j * P1_BLOCK;
        r[j] = (idx < d4) ? xr4[idx]
                          : make_float4(-INFINITY, -INFINITY, -INFINITY, -INFINITY);
    }
    float tailv = -INFINITY;               // d%4 scalar tail, last chunk only
    if (last) {
        int e = (d4 << 2) + t;
        if (e < d) tailv = xr[e];
    }

    // ---- chunk max ----
    float m = tailv;
#pragma unroll
    for (int j = 0; j < P1_NV; ++j)
        m = fmaxf(m, fmaxf(fmaxf(r[j].x, r[j].y), fmaxf(r[j].z, r[j].w)));
    m = waveReduceMax(m);
    if (lane == 0) s_red[wave] = m;
    __syncthreads();
    if (wave == 0) {
        float v = (lane < 4) ? s_red[lane] : -INFINITY;
        v = waveReduceMax(v);
        if (lane == 0) s_bcast = v;
    }
    __syncthreads();
    const float thr = s_bcast - 2.0f;

    // ---- ballot-compact candidates (raw x values) to LDS ----
#pragma unroll
    for (int j = 0; j < P1_NV; ++j) {
        float4 v = r[j];
        float mx4 = fmaxf(fmaxf(v.x, v.y), fmaxf(v.z, v.w));
        unsigned long long any = __ballot(mx4 >= thr);
        if (any) {                                    // wave-uniform branch
            float vals[4] = { v.x, v.y, v.z, v.w };
#pragma unroll
            for (int c = 0; c < 4; ++c) {
                float vv = vals[c];
                bool pred = (vv >= thr);
                unsigned long long mask = __ballot(pred);
                if (mask) {
                    int base;
                    if (lane == 0) base = atomicAdd(&s_k, __popcll(mask));
                    base = __shfl(base, 0, 64);
                    if (pred) {
                        int pos = base + (int)__popcll(mask & ((1ull << lane) - 1ull));
                        if (pos < P1_LDSCAP) s_c[pos] = vv;
                    }
                }
            }
        }
    }
    {   // scalar tail (0-trip when d%4==0)
        bool pred = (tailv >= thr);
        unsigned long long mask = __ballot(pred);
        if (mask) {
            int base;
            if (lane == 0) base = atomicAdd(&s_k, __popcll(mask));
            base = __shfl(base, 0, 64);
            if (pred) {
                int pos = base + (int)__popcll(mask & ((1ull << lane) - 1ull));
                if (pos < P1_LDSCAP) s_c[pos] = tailv;
            }
        }
    }
    __syncthreads();

    // ---- one reservation + coalesced dump to per-row workspace list ----
    const int k = min(s_k, P1_LDSCAP);
    if (t == 0) {
        s_base = atomicAdd(&cnt[row], k);
        if (s_k > P1_LDSCAP) atomicOr(&ovf[row], 1);       // LDS cap dropped data
    }
    __syncthreads();
    const int base = s_base;
    for (int i = t; i < k; i += P1_BLOCK) {
        int pos = base + i;
        if (pos < CAP_WS) cand[(size_t)row * CAP_WS + pos] = s_c[i];
    }
    if (t == 0 && base + k > CAP_WS) atomicOr(&ovf[row], 1);  // WS cap dropped data
}

// Pass 2: one 256-thr block per row; reads the tiny candidate list, rowmax =
// max of list (every chunkmax is stored), converts to u, wave0 solves.
// Overflow rows (never on bench data) re-read the row from x directly.
#define P2_CAP 6144
__global__ __launch_bounds__(P1_BLOCK, 4) void tsallis15_pass2(
    const float* __restrict__ x, const int* __restrict__ tgt,
    const float* __restrict__ cand, const int* __restrict__ cnt,
    const int* __restrict__ ovf, float* __restrict__ out,
    int n, int d, float inv_n)
{
    __shared__ float s_cand[P2_CAP];
    __shared__ float s_red[4];
    __shared__ float s_bcast;
    __shared__ int   s_k;

    const int row  = blockIdx.x;
    const int t    = threadIdx.x;
    const int lane = t & 63;
    const int wave = t >> 6;
    const int d4   = d >> 2;
    const float* __restrict__ xr = x + (size_t)row * (size_t)d;

    float xt = 0.0f;                       // lives in thread 0 (= wave0 lane0)
    if (t == 0) xt = xr[tgt[row]];

    int k;
    if (ovf[row] == 0) {
        // ---- common path: candidate list only ----
        k = min(cnt[row], CAP_WS);
        const float* rl = cand + (size_t)row * CAP_WS;
        float m = -INFINITY;
        for (int i = t; i < k; i += P1_BLOCK) {
            float v = rl[i];
            s_cand[i] = v;
            m = fmaxf(m, v);
        }
        m = waveReduceMax(m);
        if (lane == 0) s_red[wave] = m;
        __syncthreads();
        if (wave == 0) {
            float v = (lane < 4) ? s_red[lane] : -INFINITY;
            v = waveReduceMax(v);
            if (lane == 0) s_bcast = v;
        }
        __syncthreads();
        const float rowmax = s_bcast;
        for (int i = t; i < k; i += P1_BLOCK)
            s_cand[i] = (s_cand[i] - rowmax) * 0.5f;        // -> u
        __syncthreads();
        if (wave == 0) solve_wave0(s_cand, k, rowmax, xt, inv_n, out, lane);
    } else {
        // ---- fallback: re-read the row (correctness-only path) ----
        const float4* xr4 = reinterpret_cast<const float4*>(xr);
        float m = -INFINITY;
        for (int i = t; i < d4; i += P1_BLOCK) {
            float4 v = xr4[i];
            m = fmaxf(m, fmaxf(fmaxf(v.x, v.y), fmaxf(v.z, v.w)));
        }
        { int e = (d4 << 2) + t; if (e < d) m = fmaxf(m, xr[e]); }
        m = waveReduceMax(m);
        if (lane == 0) s_red[wave] = m;
        __syncthreads();
        if (wave == 0) {
            float v = (lane < 4) ? s_red[lane] : -INFINITY;
            v = waveReduceMax(v);
            if (lane == 0) s_bcast = v;
        }
        if (t == 0) s_k = 0;
        __syncthreads();
        const float rowmax = s_bcast;
        const float thr = rowmax - 2.0f;
        for (int i = t; i < d4; i += P1_BLOCK) {
            float4 v = xr4[i];
            float vals[4] = { v.x, v.y, v.z, v.w };
#pragma unroll
            for (int c = 0; c < 4; ++c) {
                float vv = vals[c];
                bool pred = (vv >= thr);
                unsigned long long mask = __ballot(pred);
                if (mask) {
                    int base;
                    if (lane == 0) base = atomicAdd(&s_k, __popcll(mask));
                    base = __shfl(base, 0, 64);
                    if (pred) {
                        int pos = base + (int)__popcll(mask & ((1ull << lane) - 1ull));
                        if (pos < P2_CAP) s_cand[pos] = (vv - rowmax) * 0.5f;
                    }
                }
            }
        }
        {   int e = (d4 << 2) + t;
            float vv = (e < d) ? xr[e] : -INFINITY;
            bool pred = (vv >= thr);
            unsigned long long mask = __ballot(pred);
            if (mask) {
                int base;
                if (lane == 0) base = atomicAdd(&s_k, __popcll(mask));
                base = __shfl(base, 0, 64);
                if (pred) {
                    int pos = base + (int)__popcll(mask & ((1ull << lane) - 1ull));
                    if (pos < P2_CAP) s_cand[pos] = (vv - rowmax) * 0.5f;
                }
            }
        }
        __syncthreads();
        k = min(s_k, P2_CAP);
        if (wave == 0) solve_wave0(s_cand, k, rowmax, xt, inv_n, out, lane);
    }
}

// ================= single-kernel fallback (R4, proven) =================
#define BLOCK 1024
#define NWAVES (BLOCK / 64)
#define NV 8
#define CAND_CAP 6144

__global__ __launch_bounds__(BLOCK, 8) void tsallis15_kernel(
    const float* __restrict__ x, const int* __restrict__ tgt,
    float* __restrict__ out, int n, int d, float inv_n)
{
    __shared__ float s_cand[CAND_CAP];
    __shared__ float s_red[NWAVES];
    __shared__ int   s_cnt;
    __shared__ float s_bcast;

    const int row  = blockIdx.x;
    const int t    = threadIdx.x;
    const int lane = t & 63;
    const int wave = t >> 6;
    const float* __restrict__ xr = x + (size_t)row * (size_t)d;

    if (t == 0) s_cnt = 0;
    float xt = 0.0f;
    if (t == 0) xt = xr[tgt[row]];

    float4 r[NV];
#pragma unroll
    for (int i = 0; i < NV; ++i) {
        int e = (i * BLOCK + t) * 4;
        if (e + 4 <= d) {
            r[i] = *reinterpret_cast<const float4*>(xr + e);
        } else {
            float4 v = make_float4(-INFINITY, -INFINITY, -INFINITY, -INFINITY);
            if (e < d)     v.x = xr[e];
            if (e + 1 < d) v.y = xr[e + 1];
            if (e + 2 < d) v.z = xr[e + 2];
            r[i] = v;
        }
    }

    float m = -INFINITY;
#pragma unroll
    for (int i = 0; i < NV; ++i)
        m = fmaxf(m, fmaxf(fmaxf(r[i].x, r[i].y), fmaxf(r[i].z, r[i].w)));
    m = waveReduceMax(m);
    if (lane == 0) s_red[wave] = m;
    __syncthreads();
    if (wave == 0) {
        float v = (lane < NWAVES) ? s_red[lane] : -INFINITY;
        v = waveReduceMax(v);
        if (lane == 0) s_bcast = v;
    }
    __syncthreads();
    const float rowmax = s_bcast;

    const float thr = rowmax - 2.0f;
#pragma unroll
    for (int i = 0; i < NV; ++i) {
        float vals[4] = { r[i].x, r[i].y, r[i].z, r[i].w };
#pragma unroll
        for (int c = 0; c < 4; ++c) {
            float v = vals[c];
            bool pred = (v >= thr);
            unsigned long long mask = __ballot(pred);
            if (mask) {
                int base;
                if (lane == 0) base = atomicAdd(&s_cnt, __popcll(mask));
                base = __shfl(base, 0, 64);
                if (pred) {
                    int pos = base + (int)__popcll(mask & ((1ull << lane) - 1ull));
                    if (pos < CAND_CAP) s_cand[pos] = (v - rowmax) * 0.5f;
                }
            }
        }
    }
    __syncthreads();

    if (wave == 0) {
        const int k = min(s_cnt, CAND_CAP);
        solve_wave0(s_cand, k, rowmax, xt, inv_n, out, lane);
    }
}

extern "C" void kernel_launch(void* const* d_in, const int* in_sizes, int n_in,
                              void* d_out, int out_size, void* d_ws, size_t ws_size,
                              hipStream_t stream) {
    const float* x   = (const float*)d_in[0];
    const int*   tgt = (const int*)d_in[1];
    float*       out = (float*)d_out;

    const int n = in_sizes[1];
    const int d = in_sizes[0] / n;
    const float inv_n = 1.0f / (float)n;

    hipMemsetAsync(out, 0, (size_t)out_size * sizeof(float), stream);

    const int d4  = d >> 2;
    int cpr = (d4 + CHUNK4 - 1) / CHUNK4;
    if (cpr < 1) cpr = 1;
    const size_t need = (size_t)n * 8 + (size_t)n * CAP_WS * 4;
    const long long nblk = (long long)n * (long long)cpr;

    if (d_ws && ws_size >= need && nblk <= 0x7FFFFFFFLL) {
        int*   cnt  = (int*)d_ws;
        int*   ovf  = cnt + n;
        float* cand = (float*)(ovf + n);
        hipMemsetAsync(d_ws, 0, (size_t)n * 8, stream);
        tsallis15_pass1<<<(int)nblk, P1_BLOCK, 0, stream>>>(x, cand, cnt, ovf, n, d, cpr);
        tsallis15_pass2<<<n, P1_BLOCK, 0, stream>>>(x, tgt, cand, cnt, ovf, out, n, d, inv_n);
    } else {
        tsallis15_kernel<<<n, BLOCK, 0, stream>>>(x, tgt, out, n, d, inv_n);
    }
}